// Round 15
// baseline (830.107 us; speedup 1.0000x reference)
//
#include <hip/hip_runtime.h>
#include <hip/hip_bf16.h>

// Problem constants
#define MROW 8192   // BATCH
#define DIMK 4096   // DIM (= K of both GEMMs)
#define NCOL 4096   // N_HEADS*HIDDEN = DIM
#define HID  256
#define NH   16
#define SEQL 4096

// GEMM: 128x128 block-tile, 4 waves (2x2 of 64x64), 256 thr, BK=32,
// ring-of-3 x 16KB = 48KB LDS -> 3 blocks/CU (12 waves): cross-block
// async overlap (m114) instead of intra-block scheduling.
#define BKT 32
#define NKT (DIMK / BKT)       // 128 K-tiles
#define SLOTB 16384            // A 8KB + B 8KB
#define NGEMM ((MROW / 128) * (NCOL / 128))   // 2048 GEMM blocks
#define NCVT 256                              // piggyback convert blocks (GEMM1)

typedef __attribute__((ext_vector_type(8))) short short8;
typedef __attribute__((ext_vector_type(4))) float f32x4;

__device__ inline ushort f2bf(float f) {
  unsigned u = __float_as_uint(f);
  u += 0x7FFF + ((u >> 16) & 1);   // RNE
  return (ushort)(u >> 16);
}

__device__ inline void gload16(const void* g, void* l) {
  __builtin_amdgcn_global_load_lds(
      (const __attribute__((address_space(1))) void*)g,
      (__attribute__((address_space(3))) void*)l, 16, 0, 0);
}

__device__ inline void cvt8(const float* __restrict__ s, ushort* __restrict__ d, long i) {
  const float4* s4 = (const float4*)(s + i * 8);
  float4 a = s4[0], b = s4[1];
  ushort r[8] = {f2bf(a.x), f2bf(a.y), f2bf(a.z), f2bf(a.w),
                 f2bf(b.x), f2bf(b.y), f2bf(b.z), f2bf(b.w)};
  *(uint4*)(d + i * 8) = *(const uint4*)r;
}

// fused x + proj_w fp32->bf16 convert + coef computation (last 16 blocks)
__global__ void cvt_xpw(const float* __restrict__ x, ushort* __restrict__ xb,
                        const float* __restrict__ pw, ushort* __restrict__ pwb,
                        const float* __restrict__ mix_w, const float* __restrict__ mix_b,
                        const float* __restrict__ decay_value, const float* __restrict__ proj_b,
                        const int* __restrict__ index_p,
                        float* __restrict__ wv, float* __restrict__ cc, float* __restrict__ pb2) {
  const int CVB = 3056;                       // convert blocks; 16 coef blocks after
  if (blockIdx.x >= CVB) {
    int n = (blockIdx.x - CVB) * 256 + threadIdx.x;   // 0..4095
    if (n < NCOL) {
      int h = n >> 8;
      int idx = *index_p;
      float w  = mix_w[h * SEQL + idx];
      float bb = mix_b[h * SEQL + idx];
      float dv = fminf(fmaxf(decay_value[h], 0.9f), 1.0f);
      float decay = powf(dv, 0.125f);         // 1/DECAY_CONSTANT (=8)
      wv[n]  = w;
      cc[n]  = (h < NH / 2) ? w * decay : decay;
      pb2[n] = w * proj_b[n] + bb;
    }
    return;
  }
  const long n8x = (long)MROW * DIMK / 8;
  const long n8p = (long)NCOL * DIMK / 8;
  long stride = (long)CVB * blockDim.x;
  for (long i = (long)blockIdx.x * blockDim.x + threadIdx.x; i < n8x + n8p; i += stride) {
    if (i < n8x) cvt8(x, xb, i);
    else         cvt8(pw, pwb, i - n8x);
  }
}

// C = A(MxK)*B^T(NxK), bf16, 16x16x32 MFMA. Swizzle: 16B slot = c ^ ((row>>1)&3)
// (measured 0 conflicts), inverse on the global staging source (linear LDS dest),
// forward on reads. Ring-of-3, lead-2 prefetch, counted vmcnt(4) per tile.
// 3 blocks/CU: other blocks' MFMA hides this block's staging/barriers (m114).
// GEMM1 carries NCVT piggyback blocks converting out_w under spare HBM BW.
template <int EPI>
__global__ __launch_bounds__(256, 3) void gemm128(
    const ushort* __restrict__ A, const ushort* __restrict__ B,
    float* __restrict__ outf, ushort* __restrict__ outh,
    const float* __restrict__ cache, const float* __restrict__ wv,
    const float* __restrict__ cc, const float* __restrict__ pb2,
    const float* __restrict__ outb,
    const float* __restrict__ owsrc, ushort* __restrict__ owdst) {
  __shared__ __align__(16) char smem[3 * SLOTB];

  const int bid = blockIdx.x;
  if (EPI == 1 && bid >= NGEMM) {
    const long n8 = (long)NCOL * DIMK / 8;
    long stride = (long)NCVT * blockDim.x;
    for (long i = (long)(bid - NGEMM) * blockDim.x + threadIdx.x; i < n8; i += stride)
      cvt8(owsrc, owdst, i);
    return;
  }

  const int tid  = threadIdx.x;
  const int lane = tid & 63;
  const int wid  = tid >> 6;      // 0..3
  const int wr = wid >> 1;        // 0..1 (M)
  const int wc = wid & 1;         // 0..1 (N)
  const int r16 = lane & 15;
  const int cq  = lane >> 4;      // 16B column block 0..3

  // XCD swizzle (2048 GEMM blocks, bijective)
  const int swz = (bid & 7) * 256 + (bid >> 3);
  const int bm = swz >> 5, bn = swz & 31;   // 64 x 32 tiles
  const int m0 = bm * 128, n0 = bn * 128;

  const ushort* Ag = A + (size_t)m0 * DIMK;
  const ushort* Bg = B + (size_t)n0 * DIMK;

  // ---- precomputed LDS read byte-offsets (loop-invariant; swizzled)
  int aoff[4], boff[4];
#pragma unroll
  for (int i = 0; i < 4; ++i) {
    int arow = wr * 64 + i * 16 + r16;
    aoff[i] = arow * 64 + ((cq ^ ((arow >> 1) & 3)) << 4);
    int brow = wc * 64 + i * 16 + r16;
    boff[i] = 8192 + brow * 64 + ((cq ^ ((brow >> 1) & 3)) << 4);
  }

  // ---- stage offsets: linear LDS dest, inverse-swizzled global src
  int soff[2], sgo[2];
#pragma unroll
  for (int j = 0; j < 2; ++j) {
    int off = j * 4096 + tid * 16;             // [0, 8192)
    int row = off >> 6;                        // 0..127
    soff[j] = off;
    sgo[j]  = row * DIMK + ((((off >> 4) & 3) ^ ((row >> 1) & 3)) << 3);
  }

  f32x4 acc[4][4] = {};

  // prologue: stage tiles 0,1 into slots 0,1 (4 gloads each)
#pragma unroll
  for (int kt = 0; kt < 2; ++kt) {
    char* s = smem + kt * SLOTB;
#pragma unroll
    for (int j = 0; j < 2; ++j) {
      gload16(Ag + (size_t)sgo[j] + kt * BKT, s + soff[j]);
      gload16(Bg + (size_t)sgo[j] + kt * BKT, s + 8192 + soff[j]);
    }
  }
  asm volatile("s_waitcnt vmcnt(4)" ::: "memory");   // tile 0 landed
  __builtin_amdgcn_s_barrier();
  __builtin_amdgcn_sched_barrier(0);

  int rcur = 0, rstg = 2;
  for (int kt = 0; kt < NKT; ++kt) {
    const char* cur = smem + rcur * SLOTB;

    short8 af[4], bf[4];
#pragma unroll
    for (int i = 0; i < 4; ++i) bf[i] = *(const short8*)(cur + boff[i]);
#pragma unroll
    for (int i = 0; i < 4; ++i) af[i] = *(const short8*)(cur + aoff[i]);

    // prefetch tile kt+2 into slot rstg (tile kt-1's slot, consumed last iter)
    if (kt < NKT - 2) {
      char* st = smem + rstg * SLOTB;
      int k0 = (kt + 2) * BKT;
#pragma unroll
      for (int j = 0; j < 2; ++j) {
        gload16(Ag + (size_t)sgo[j] + k0, st + soff[j]);
        gload16(Bg + (size_t)sgo[j] + k0, st + 8192 + soff[j]);
      }
    }

    __builtin_amdgcn_s_setprio(1);
#pragma unroll
    for (int mi = 0; mi < 4; ++mi)
#pragma unroll
      for (int ni = 0; ni < 4; ++ni)
        acc[mi][ni] = __builtin_amdgcn_mfma_f32_16x16x32_bf16(af[mi], bf[ni], acc[mi][ni], 0, 0, 0);
    __builtin_amdgcn_s_setprio(0);

    // counted wait: tile kt+1 landed; tile kt+2's loads stay in flight.
    if (kt < NKT - 2)       asm volatile("s_waitcnt vmcnt(4)" ::: "memory");
    else if (kt == NKT - 2) asm volatile("s_waitcnt vmcnt(0)" ::: "memory");
    __builtin_amdgcn_s_barrier();
    __builtin_amdgcn_sched_barrier(0);

    rcur = (rcur == 2) ? 0 : rcur + 1;
    rstg = (rstg == 2) ? 0 : rstg + 1;
  }

  // ---- epilogue. C/D 16x16 map: col = lane&15, row = (lane>>4)*4 + reg
  const int colb = n0 + wc * 64 + r16;
  const int rowb = m0 + wr * 64 + cq * 4;

  float wvv[4], ccv[4], pbv[4], obv[4];
#pragma unroll
  for (int ni = 0; ni < 4; ++ni) {
    int n = colb + ni * 16;
    if (EPI == 1) { wvv[ni] = wv[n]; ccv[ni] = cc[n]; pbv[ni] = pb2[n]; }
    else          { obv[ni] = outb[n]; }
  }

#pragma unroll
  for (int mi = 0; mi < 4; ++mi) {
#pragma unroll
    for (int ni = 0; ni < 4; ++ni) {
      f32x4 v = acc[mi][ni];
      int n = colb + ni * 16;
#pragma unroll
      for (int r = 0; r < 4; ++r) {
        int m = rowb + mi * 16 + r;
        if (EPI == 1) {
          int h = n >> 8, kq = n & 255;
          float val = wvv[ni] * v[r] + ccv[ni] * cache[((size_t)h * MROW + m) * HID + kq] + pbv[ni];
          outh[(size_t)m * NCOL + n] = f2bf(val);
        } else {
          outf[(size_t)m * NCOL + n] = v[r] + obv[ni];
        }
      }
    }
  }
}

extern "C" void kernel_launch(void* const* d_in, const int* in_sizes, int n_in,
                              void* d_out, int out_size, void* d_ws, size_t ws_size,
                              hipStream_t stream) {
  const float* x      = (const float*)d_in[0];
  const float* proj_w = (const float*)d_in[1];
  const float* proj_b = (const float*)d_in[2];
  const float* mix_w  = (const float*)d_in[3];
  const float* mix_b  = (const float*)d_in[4];
  const float* decay  = (const float*)d_in[5];
  const float* cache  = (const float*)d_in[6];
  const float* out_w  = (const float*)d_in[7];
  const float* out_b  = (const float*)d_in[8];
  const int*   index  = (const int*)d_in[9];

  char* ws = (char*)d_ws;
  ushort* xb  = (ushort*)ws;                         // 64 MiB
  ushort* pwb = (ushort*)(ws + 67108864);            // 32 MiB
  ushort* owb = (ushort*)(ws + 100663296);           // 32 MiB
  ushort* hid = (ushort*)(ws + 134217728);           // 64 MiB
  float*  wv  = (float*)(ws + 201326592);
  float*  cc  = (float*)(ws + 201326592 + 16384);
  float*  pb2 = (float*)(ws + 201326592 + 32768);

  // fused x + proj_w convert + coef (ow convert rides inside GEMM1)
  hipLaunchKernelGGL(cvt_xpw, dim3(3072), dim3(256), 0, stream,
                     x, xb, proj_w, pwb,
                     mix_w, mix_b, decay, proj_b, index, wv, cc, pb2);

  // GEMM1 (+ piggyback ow-convert blocks): hidden = mix(x @ proj_w^T) -> bf16
  hipLaunchKernelGGL((gemm128<1>), dim3(NGEMM + NCVT), dim3(256), 0, stream,
                     xb, pwb, nullptr, hid, cache, wv, cc, pb2, nullptr, out_w, owb);
  // GEMM2: out = hidden @ out_w^T + out_b -> f32
  hipLaunchKernelGGL((gemm128<0>), dim3(NGEMM), dim3(256), 0, stream,
                     hid, owb, (float*)d_out, nullptr, nullptr, nullptr, nullptr, nullptr, out_b,
                     nullptr, nullptr);
}

// Round 16
// 618.564 us; speedup vs baseline: 1.3420x; 1.3420x over previous
//
#include <hip/hip_runtime.h>
#include <hip/hip_bf16.h>

// Problem constants
#define MROW 8192   // BATCH
#define DIMK 4096   // DIM (= K of both GEMMs)
#define NCOL 4096   // N_HEADS*HIDDEN = DIM
#define HID  256
#define NH   16
#define SEQL 4096

// GEMM: 256x256 tile, BK=32, 16 waves (4M x 4N, wave 64x64), ring-of-4 LDS,
// LEAD-2 staging + ONE barrier per TWO K-tiles: waves skew within the 2-tile
// window so one wave's MFMA overlaps another's LDS reads (the 8 schedules with
// per-tile barriers all phase-locked at 44% MfmaUtil).
#define BKT 32
#define NKT (DIMK / BKT)       // 128 K-tiles
#define SLOTB 32768            // ring slot: A 16KB + B 16KB
#define LDS_TOTAL (4 * SLOTB)  // 131072
#define NGEMM ((MROW / 256) * (NCOL / 256))   // 512 GEMM blocks
#define NCVT 256                              // piggyback convert blocks (GEMM1)

typedef __attribute__((ext_vector_type(8))) short short8;
typedef __attribute__((ext_vector_type(4))) float f32x4;

__device__ inline ushort f2bf(float f) {
  unsigned u = __float_as_uint(f);
  u += 0x7FFF + ((u >> 16) & 1);   // RNE
  return (ushort)(u >> 16);
}

__device__ inline void gload16(const void* g, void* l) {
  __builtin_amdgcn_global_load_lds(
      (const __attribute__((address_space(1))) void*)g,
      (__attribute__((address_space(3))) void*)l, 16, 0, 0);
}

__device__ inline void cvt8(const float* __restrict__ s, ushort* __restrict__ d, long i) {
  const float4* s4 = (const float4*)(s + i * 8);
  float4 a = s4[0], b = s4[1];
  ushort r[8] = {f2bf(a.x), f2bf(a.y), f2bf(a.z), f2bf(a.w),
                 f2bf(b.x), f2bf(b.y), f2bf(b.z), f2bf(b.w)};
  *(uint4*)(d + i * 8) = *(const uint4*)r;
}

// fused x + proj_w fp32->bf16 convert + coef computation (last 16 blocks)
__global__ void cvt_xpw(const float* __restrict__ x, ushort* __restrict__ xb,
                        const float* __restrict__ pw, ushort* __restrict__ pwb,
                        const float* __restrict__ mix_w, const float* __restrict__ mix_b,
                        const float* __restrict__ decay_value, const float* __restrict__ proj_b,
                        const int* __restrict__ index_p,
                        float* __restrict__ wv, float* __restrict__ cc, float* __restrict__ pb2) {
  const int CVB = 3056;                       // convert blocks; 16 coef blocks after
  if (blockIdx.x >= CVB) {
    int n = (blockIdx.x - CVB) * 256 + threadIdx.x;   // 0..4095
    if (n < NCOL) {
      int h = n >> 8;
      int idx = *index_p;
      float w  = mix_w[h * SEQL + idx];
      float bb = mix_b[h * SEQL + idx];
      float dv = fminf(fmaxf(decay_value[h], 0.9f), 1.0f);
      float decay = powf(dv, 0.125f);         // 1/DECAY_CONSTANT (=8)
      wv[n]  = w;
      cc[n]  = (h < NH / 2) ? w * decay : decay;
      pb2[n] = w * proj_b[n] + bb;
    }
    return;
  }
  const long n8x = (long)MROW * DIMK / 8;
  const long n8p = (long)NCOL * DIMK / 8;
  long stride = (long)CVB * blockDim.x;
  for (long i = (long)blockIdx.x * blockDim.x + threadIdx.x; i < n8x + n8p; i += stride) {
    if (i < n8x) cvt8(x, xb, i);
    else         cvt8(pw, pwb, i - n8x);
  }
}

// C = A(MxK)*B^T(NxK), bf16, 16x16x32 MFMA. Swizzle: 16B slot = c ^ ((row>>1)&3)
// (measured 0 conflicts), inverse on the global staging source (linear LDS dest).
// Ring-of-4, LEAD-2 prefetch, barrier + vmcnt(0) once per 2-tile window.
// Safety: WAR — stage(kt+2) hits the slot last read at kt-2; one barrier always
// separates. RAW — window-end vmcnt(0)+barrier covers both next-window tiles.
// GEMM1 carries NCVT piggyback blocks converting out_w under spare HBM BW.
template <int EPI>
__global__ __launch_bounds__(1024, 4) void gemm256(
    const ushort* __restrict__ A, const ushort* __restrict__ B,
    float* __restrict__ outf, ushort* __restrict__ outh,
    const float* __restrict__ cache, const float* __restrict__ wv,
    const float* __restrict__ cc, const float* __restrict__ pb2,
    const float* __restrict__ outb,
    const float* __restrict__ owsrc, ushort* __restrict__ owdst) {
  extern __shared__ __align__(16) char smem[];

  const int bid = blockIdx.x;
  if (EPI == 1 && bid >= NGEMM) {
    const long n8 = (long)NCOL * DIMK / 8;
    long stride = (long)NCVT * blockDim.x;
    for (long i = (long)(bid - NGEMM) * blockDim.x + threadIdx.x; i < n8; i += stride)
      cvt8(owsrc, owdst, i);
    return;
  }

  const int tid  = threadIdx.x;
  const int lane = tid & 63;
  const int wid  = tid >> 6;      // 0..15
  const int wr = wid >> 2;        // 0..3 (M)
  const int wc = wid & 3;         // 0..3 (N)
  const int r16 = lane & 15;
  const int cq  = lane >> 4;      // 16B column block 0..3

  // XCD swizzle (512 GEMM blocks, bijective)
  const int swz = (bid & 7) * 64 + (bid >> 3);
  const int bm = swz >> 4, bn = swz & 15;   // 32 x 16 tiles
  const int m0 = bm * 256, n0 = bn * 256;

  const ushort* Ag = A + (size_t)m0 * DIMK;
  const ushort* Bg = B + (size_t)n0 * DIMK;

  // ---- precomputed LDS read byte-offsets (loop-invariant; swizzled)
  int aoff[4], boff[4];
#pragma unroll
  for (int i = 0; i < 4; ++i) {
    int arow = wr * 64 + i * 16 + r16;
    aoff[i] = arow * 64 + ((cq ^ ((arow >> 1) & 3)) << 4);
    int brow = wc * 64 + i * 16 + r16;
    boff[i] = 16384 + brow * 64 + ((cq ^ ((brow >> 1) & 3)) << 4);
  }

  // ---- precomputed stage offsets: linear LDS dest, inverse-swizzled global src
  const int soff = tid * 16;                 // [0, 16384)
  const int srow = soff >> 6;
  const int sgo  = srow * DIMK + ((((soff >> 4) & 3) ^ ((srow >> 1) & 3)) << 3);

  f32x4 acc[4][4] = {};

  // prologue: stage K-tiles 0,1 into slots 0,1; drain; barrier.
#pragma unroll
  for (int kt = 0; kt < 2; ++kt) {
    char* s = smem + kt * SLOTB;
    gload16(Ag + (size_t)sgo + kt * BKT, s + soff);
    gload16(Bg + (size_t)sgo + kt * BKT, s + 16384 + soff);
  }
  asm volatile("s_waitcnt vmcnt(0)" ::: "memory");
  __builtin_amdgcn_s_barrier();
  __builtin_amdgcn_sched_barrier(0);

  for (int j2 = 0; j2 < NKT; j2 += 2) {
    // ---- tile j2 (no barrier at end: waves may skew into tile j2+1)
    {
      const char* cur = smem + (j2 & 3) * SLOTB;
      short8 af[4], bf[4];
#pragma unroll
      for (int i = 0; i < 4; ++i) bf[i] = *(const short8*)(cur + boff[i]);
#pragma unroll
      for (int i = 0; i < 4; ++i) af[i] = *(const short8*)(cur + aoff[i]);
      if (j2 + 2 < NKT) {
        char* st = smem + ((j2 + 2) & 3) * SLOTB;
        int k0 = (j2 + 2) * BKT;
        gload16(Ag + (size_t)sgo + k0, st + soff);
        gload16(Bg + (size_t)sgo + k0, st + 16384 + soff);
      }
      __builtin_amdgcn_s_setprio(1);
#pragma unroll
      for (int mi = 0; mi < 4; ++mi)
#pragma unroll
        for (int ni = 0; ni < 4; ++ni)
          acc[mi][ni] = __builtin_amdgcn_mfma_f32_16x16x32_bf16(af[mi], bf[ni], acc[mi][ni], 0, 0, 0);
      __builtin_amdgcn_s_setprio(0);
    }
    // ---- tile j2+1
    {
      const char* cur = smem + ((j2 + 1) & 3) * SLOTB;
      short8 af[4], bf[4];
#pragma unroll
      for (int i = 0; i < 4; ++i) bf[i] = *(const short8*)(cur + boff[i]);
#pragma unroll
      for (int i = 0; i < 4; ++i) af[i] = *(const short8*)(cur + aoff[i]);
      if (j2 + 3 < NKT) {
        char* st = smem + ((j2 + 3) & 3) * SLOTB;
        int k0 = (j2 + 3) * BKT;
        gload16(Ag + (size_t)sgo + k0, st + soff);
        gload16(Bg + (size_t)sgo + k0, st + 16384 + soff);
      }
      __builtin_amdgcn_s_setprio(1);
#pragma unroll
      for (int mi = 0; mi < 4; ++mi)
#pragma unroll
        for (int ni = 0; ni < 4; ++ni)
          acc[mi][ni] = __builtin_amdgcn_mfma_f32_16x16x32_bf16(af[mi], bf[ni], acc[mi][ni], 0, 0, 0);
      __builtin_amdgcn_s_setprio(0);
    }

    // window end: both next-window tiles (j2+2, j2+3) must be landed for ALL
    // waves -> vmcnt(0) + barrier. Youngest load is ~1 tile old, so the drain
    // is near-free in steady state.
    asm volatile("s_waitcnt vmcnt(0)" ::: "memory");
    __builtin_amdgcn_s_barrier();
    __builtin_amdgcn_sched_barrier(0);
  }

  // ---- epilogue. C/D 16x16 map: col = lane&15, row = (lane>>4)*4 + reg
  const int colb = n0 + wc * 64 + r16;
  const int rowb = m0 + wr * 64 + cq * 4;

  float wvv[4], ccv[4], pbv[4], obv[4];
#pragma unroll
  for (int ni = 0; ni < 4; ++ni) {
    int n = colb + ni * 16;
    if (EPI == 1) { wvv[ni] = wv[n]; ccv[ni] = cc[n]; pbv[ni] = pb2[n]; }
    else          { obv[ni] = outb[n]; }
  }

#pragma unroll
  for (int mi = 0; mi < 4; ++mi) {
#pragma unroll
    for (int ni = 0; ni < 4; ++ni) {
      f32x4 v = acc[mi][ni];
      int n = colb + ni * 16;
#pragma unroll
      for (int r = 0; r < 4; ++r) {
        int m = rowb + mi * 16 + r;
        if (EPI == 1) {
          int h = n >> 8, kq = n & 255;
          float val = wvv[ni] * v[r] + ccv[ni] * cache[((size_t)h * MROW + m) * HID + kq] + pbv[ni];
          outh[(size_t)m * NCOL + n] = f2bf(val);
        } else {
          outf[(size_t)m * NCOL + n] = v[r] + obv[ni];
        }
      }
    }
  }
}

extern "C" void kernel_launch(void* const* d_in, const int* in_sizes, int n_in,
                              void* d_out, int out_size, void* d_ws, size_t ws_size,
                              hipStream_t stream) {
  const float* x      = (const float*)d_in[0];
  const float* proj_w = (const float*)d_in[1];
  const float* proj_b = (const float*)d_in[2];
  const float* mix_w  = (const float*)d_in[3];
  const float* mix_b  = (const float*)d_in[4];
  const float* decay  = (const float*)d_in[5];
  const float* cache  = (const float*)d_in[6];
  const float* out_w  = (const float*)d_in[7];
  const float* out_b  = (const float*)d_in[8];
  const int*   index  = (const int*)d_in[9];

  char* ws = (char*)d_ws;
  ushort* xb  = (ushort*)ws;                         // 64 MiB
  ushort* pwb = (ushort*)(ws + 67108864);            // 32 MiB
  ushort* owb = (ushort*)(ws + 100663296);           // 32 MiB
  ushort* hid = (ushort*)(ws + 134217728);           // 64 MiB
  float*  wv  = (float*)(ws + 201326592);
  float*  cc  = (float*)(ws + 201326592 + 16384);
  float*  pb2 = (float*)(ws + 201326592 + 32768);

  hipFuncSetAttribute((const void*)&gemm256<1>, hipFuncAttributeMaxDynamicSharedMemorySize, LDS_TOTAL);
  hipFuncSetAttribute((const void*)&gemm256<0>, hipFuncAttributeMaxDynamicSharedMemorySize, LDS_TOTAL);

  // fused x + proj_w convert + coef (ow convert rides inside GEMM1)
  hipLaunchKernelGGL(cvt_xpw, dim3(3072), dim3(256), 0, stream,
                     x, xb, proj_w, pwb,
                     mix_w, mix_b, decay, proj_b, index, wv, cc, pb2);

  // GEMM1 (+ piggyback ow-convert blocks): hidden = mix(x @ proj_w^T) -> bf16
  hipLaunchKernelGGL((gemm256<1>), dim3(NGEMM + NCVT), dim3(1024), LDS_TOTAL, stream,
                     xb, pwb, nullptr, hid, cache, wv, cc, pb2, nullptr, out_w, owb);
  // GEMM2: out = hidden @ out_w^T + out_b -> f32
  hipLaunchKernelGGL((gemm256<0>), dim3(NGEMM), dim3(1024), LDS_TOTAL, stream,
                     hid, owb, (float*)d_out, nullptr, nullptr, nullptr, nullptr, nullptr, out_b,
                     nullptr, nullptr);
}

// Round 17
// 585.796 us; speedup vs baseline: 1.4171x; 1.0559x over previous
//
#include <hip/hip_runtime.h>
#include <hip/hip_bf16.h>

// Problem constants
#define MROW 8192   // BATCH
#define DIMK 4096   // DIM (= K of both GEMMs)
#define NCOL 4096   // N_HEADS*HIDDEN = DIM
#define HID  256
#define NH   16
#define SEQL 4096

// GEMM tile geometry (R14/best-measured): 256x256 tile, BK=32, 16 waves
// (4M x 4N, wave-tile 64x64), ring-of-4 LDS (4 x 32KB = 128KB), 1 block/CU,
// lead-3 prefetch with counted vmcnt(4) that never drains in steady state.
#define BKT 32
#define NKT (DIMK / BKT)       // 128 K-tiles
#define SLOTB 32768            // ring slot: A 16KB + B 16KB
#define LDS_TOTAL (4 * SLOTB)  // 131072
#define NGEMM ((MROW / 256) * (NCOL / 256))   // 512 GEMM blocks
#define NCVT 256                              // piggyback convert blocks (GEMM1)

typedef __attribute__((ext_vector_type(8))) short short8;
typedef __attribute__((ext_vector_type(4))) float f32x4;

__device__ inline ushort f2bf(float f) {
  unsigned u = __float_as_uint(f);
  u += 0x7FFF + ((u >> 16) & 1);   // RNE
  return (ushort)(u >> 16);
}

__device__ inline void gload16(const void* g, void* l) {
  __builtin_amdgcn_global_load_lds(
      (const __attribute__((address_space(1))) void*)g,
      (__attribute__((address_space(3))) void*)l, 16, 0, 0);
}

__device__ inline void cvt8(const float* __restrict__ s, ushort* __restrict__ d, long i) {
  const float4* s4 = (const float4*)(s + i * 8);
  float4 a = s4[0], b = s4[1];
  ushort r[8] = {f2bf(a.x), f2bf(a.y), f2bf(a.z), f2bf(a.w),
                 f2bf(b.x), f2bf(b.y), f2bf(b.z), f2bf(b.w)};
  *(uint4*)(d + i * 8) = *(const uint4*)r;
}

// fused x + proj_w fp32->bf16 convert + coef computation (last 16 blocks)
__global__ void cvt_xpw(const float* __restrict__ x, ushort* __restrict__ xb,
                        const float* __restrict__ pw, ushort* __restrict__ pwb,
                        const float* __restrict__ mix_w, const float* __restrict__ mix_b,
                        const float* __restrict__ decay_value, const float* __restrict__ proj_b,
                        const int* __restrict__ index_p,
                        float* __restrict__ wv, float* __restrict__ cc, float* __restrict__ pb2) {
  const int CVB = 3056;                       // convert blocks; 16 coef blocks after
  if (blockIdx.x >= CVB) {
    int n = (blockIdx.x - CVB) * 256 + threadIdx.x;   // 0..4095
    if (n < NCOL) {
      int h = n >> 8;
      int idx = *index_p;
      float w  = mix_w[h * SEQL + idx];
      float bb = mix_b[h * SEQL + idx];
      float dv = fminf(fmaxf(decay_value[h], 0.9f), 1.0f);
      float decay = powf(dv, 0.125f);         // 1/DECAY_CONSTANT (=8)
      wv[n]  = w;
      cc[n]  = (h < NH / 2) ? w * decay : decay;
      pb2[n] = w * proj_b[n] + bb;
    }
    return;
  }
  const long n8x = (long)MROW * DIMK / 8;
  const long n8p = (long)NCOL * DIMK / 8;
  long stride = (long)CVB * blockDim.x;
  for (long i = (long)blockIdx.x * blockDim.x + threadIdx.x; i < n8x + n8p; i += stride) {
    if (i < n8x) cvt8(x, xb, i);
    else         cvt8(pw, pwb, i - n8x);
  }
}

// C = A(MxK)*B^T(NxK), bf16, 16x16x32 MFMA (best-measured R14 structure).
// LDS tile row = 64B, swizzle 16B slot = c ^ ((row>>1)&3) (measured 0
// conflicts), inverse-applied on the global staging source (linear LDS dest
// for global_load_lds), forward on reads. 16 waves, one barrier per K-tile,
// counted vmcnt held across barriers (never drains in steady state), ring-of-4.
// GEMM1 carries NCVT piggyback blocks converting out_w under spare HBM BW.
template <int EPI>
__global__ __launch_bounds__(1024, 4) void gemm256(
    const ushort* __restrict__ A, const ushort* __restrict__ B,
    float* __restrict__ outf, ushort* __restrict__ outh,
    const float* __restrict__ cache, const float* __restrict__ wv,
    const float* __restrict__ cc, const float* __restrict__ pb2,
    const float* __restrict__ outb,
    const float* __restrict__ owsrc, ushort* __restrict__ owdst) {
  extern __shared__ __align__(16) char smem[];

  const int bid = blockIdx.x;
  if (EPI == 1 && bid >= NGEMM) {
    // ---- piggyback: convert out_w for GEMM2 (rides GEMM1's idle HBM pipe)
    const long n8 = (long)NCOL * DIMK / 8;   // 2097152
    long stride = (long)NCVT * blockDim.x;
    for (long i = (long)(bid - NGEMM) * blockDim.x + threadIdx.x; i < n8; i += stride)
      cvt8(owsrc, owdst, i);
    return;
  }

  const int tid  = threadIdx.x;
  const int lane = tid & 63;
  const int wid  = tid >> 6;      // 0..15
  const int wr = wid >> 2;        // 0..3 (M)
  const int wc = wid & 3;         // 0..3 (N)
  const int r16 = lane & 15;
  const int cq  = lane >> 4;      // 16B column block 0..3

  // XCD swizzle (512 GEMM blocks, bijective)
  const int swz = (bid & 7) * 64 + (bid >> 3);
  const int bm = swz >> 4, bn = swz & 15;   // 32 x 16 tiles
  const int m0 = bm * 256, n0 = bn * 256;

  const ushort* Ag = A + (size_t)m0 * DIMK;
  const ushort* Bg = B + (size_t)n0 * DIMK;

  // ---- precomputed LDS read byte-offsets (loop-invariant; swizzled)
  int aoff[4], boff[4];
#pragma unroll
  for (int i = 0; i < 4; ++i) {
    int arow = wr * 64 + i * 16 + r16;
    aoff[i] = arow * 64 + ((cq ^ ((arow >> 1) & 3)) << 4);
    int brow = wc * 64 + i * 16 + r16;
    boff[i] = 16384 + brow * 64 + ((cq ^ ((brow >> 1) & 3)) << 4);
  }

  // ---- precomputed stage offsets: linear LDS dest, inverse-swizzled global src
  const int soff = tid * 16;                 // [0, 16384)
  const int srow = soff >> 6;
  const int sgo  = srow * DIMK + ((((soff >> 4) & 3) ^ ((srow >> 1) & 3)) << 3);

  f32x4 acc[4][4] = {};

  // prologue: stage K-tiles 0..2 into ring slots 0..2 (2 loads per thread per kt)
#pragma unroll
  for (int kt = 0; kt < 3; ++kt) {
    char* s = smem + kt * SLOTB;
    gload16(Ag + (size_t)sgo + kt * BKT, s + soff);
    gload16(Bg + (size_t)sgo + kt * BKT, s + 16384 + soff);
  }
  asm volatile("s_waitcnt vmcnt(4)" ::: "memory");   // kt0 landed
  __builtin_amdgcn_s_barrier();
  __builtin_amdgcn_sched_barrier(0);

  for (int kt = 0; kt < NKT; ++kt) {
    const char* cur = smem + (kt & 3) * SLOTB;

    short8 af[4], bf[4];
#pragma unroll
    for (int i = 0; i < 4; ++i) bf[i] = *(const short8*)(cur + boff[i]);
#pragma unroll
    for (int i = 0; i < 4; ++i) af[i] = *(const short8*)(cur + aoff[i]);

    // prefetch K-tile kt+3 into ring slot (kt+3)&3 (= (kt-1)&3, consumed last iter)
    if (kt < NKT - 3) {
      char* st = smem + ((kt + 3) & 3) * SLOTB;
      int k0 = (kt + 3) * BKT;
      gload16(Ag + (size_t)sgo + k0, st + soff);
      gload16(Bg + (size_t)sgo + k0, st + 16384 + soff);
    }

    __builtin_amdgcn_s_setprio(1);
#pragma unroll
    for (int mi = 0; mi < 4; ++mi)
#pragma unroll
      for (int ni = 0; ni < 4; ++ni)
        acc[mi][ni] = __builtin_amdgcn_mfma_f32_16x16x32_bf16(af[mi], bf[ni], acc[mi][ni], 0, 0, 0);
    __builtin_amdgcn_s_setprio(0);

    // counted wait: guarantee kt+1 landed; deeper prefetch stays in flight
    // across the barrier (never drains to 0 in steady state).
    if (kt < NKT - 3)       asm volatile("s_waitcnt vmcnt(4)" ::: "memory");
    else if (kt == NKT - 3) asm volatile("s_waitcnt vmcnt(2)" ::: "memory");
    else if (kt == NKT - 2) asm volatile("s_waitcnt vmcnt(0)" ::: "memory");
    __builtin_amdgcn_s_barrier();
    __builtin_amdgcn_sched_barrier(0);
  }

  // ---- epilogue. C/D 16x16 map: col = lane&15, row = (lane>>4)*4 + reg
  const int colb = n0 + wc * 64 + r16;
  const int rowb = m0 + wr * 64 + cq * 4;

  float wvv[4], ccv[4], pbv[4], obv[4];
#pragma unroll
  for (int ni = 0; ni < 4; ++ni) {
    int n = colb + ni * 16;
    if (EPI == 1) { wvv[ni] = wv[n]; ccv[ni] = cc[n]; pbv[ni] = pb2[n]; }
    else          { obv[ni] = outb[n]; }
  }

#pragma unroll
  for (int mi = 0; mi < 4; ++mi) {
#pragma unroll
    for (int ni = 0; ni < 4; ++ni) {
      f32x4 v = acc[mi][ni];
      int n = colb + ni * 16;
#pragma unroll
      for (int r = 0; r < 4; ++r) {
        int m = rowb + mi * 16 + r;
        if (EPI == 1) {
          int h = n >> 8, kq = n & 255;
          float val = wvv[ni] * v[r] + ccv[ni] * cache[((size_t)h * MROW + m) * HID + kq] + pbv[ni];
          outh[(size_t)m * NCOL + n] = f2bf(val);
        } else {
          outf[(size_t)m * NCOL + n] = v[r] + obv[ni];
        }
      }
    }
  }
}

extern "C" void kernel_launch(void* const* d_in, const int* in_sizes, int n_in,
                              void* d_out, int out_size, void* d_ws, size_t ws_size,
                              hipStream_t stream) {
  const float* x      = (const float*)d_in[0];
  const float* proj_w = (const float*)d_in[1];
  const float* proj_b = (const float*)d_in[2];
  const float* mix_w  = (const float*)d_in[3];
  const float* mix_b  = (const float*)d_in[4];
  const float* decay  = (const float*)d_in[5];
  const float* cache  = (const float*)d_in[6];
  const float* out_w  = (const float*)d_in[7];
  const float* out_b  = (const float*)d_in[8];
  const int*   index  = (const int*)d_in[9];

  char* ws = (char*)d_ws;
  ushort* xb  = (ushort*)ws;                         // 64 MiB
  ushort* pwb = (ushort*)(ws + 67108864);            // 32 MiB
  ushort* owb = (ushort*)(ws + 100663296);           // 32 MiB
  ushort* hid = (ushort*)(ws + 134217728);           // 64 MiB
  float*  wv  = (float*)(ws + 201326592);
  float*  cc  = (float*)(ws + 201326592 + 16384);
  float*  pb2 = (float*)(ws + 201326592 + 32768);

  hipFuncSetAttribute((const void*)&gemm256<1>, hipFuncAttributeMaxDynamicSharedMemorySize, LDS_TOTAL);
  hipFuncSetAttribute((const void*)&gemm256<0>, hipFuncAttributeMaxDynamicSharedMemorySize, LDS_TOTAL);

  // fused x + proj_w convert + coef (ow convert rides inside GEMM1)
  hipLaunchKernelGGL(cvt_xpw, dim3(3072), dim3(256), 0, stream,
                     x, xb, proj_w, pwb,
                     mix_w, mix_b, decay, proj_b, index, wv, cc, pb2);

  // GEMM1 (+ piggyback ow-convert blocks): hidden = mix(x @ proj_w^T) -> bf16
  hipLaunchKernelGGL((gemm256<1>), dim3(NGEMM + NCVT), dim3(1024), LDS_TOTAL, stream,
                     xb, pwb, nullptr, hid, cache, wv, cc, pb2, nullptr, out_w, owb);
  // GEMM2: out = hidden @ out_w^T + out_b -> f32
  hipLaunchKernelGGL((gemm256<0>), dim3(NGEMM), dim3(1024), LDS_TOTAL, stream,
                     hid, owb, (float*)d_out, nullptr, nullptr, nullptr, nullptr, nullptr, out_b,
                     nullptr, nullptr);
}